// Round 2
// baseline (29418.137 us; speedup 1.0000x reference)
//
#include <hip/hip_runtime.h>
#include <math.h>

#define BB 32
#define SS 512
#define EE 256
#define HH 512
#define VV 32000
#define TT 30

__device__ __forceinline__ float4 ldf4(const float* p) {
    return *reinterpret_cast<const float4*>(p);
}
__device__ __forceinline__ float dot4(float4 a, float4 b) {
    return a.x * b.x + a.y * b.y + a.z * b.z + a.w * b.w;
}
__device__ __forceinline__ float sigmoidf_(float x) {
    return 1.0f / (1.0f + expf(-x));
}

// ---------------------------------------------------------------------------
// Encoder single step (both directions). grid = 128 blocks x 256 threads.
//   bid>>6 = dir (0 fwd, 1 bwd); (bid&63)*8 = j-chunk base.
//   thread: b = tid&31, slot = tid>>5 (0..7), j = jc + slot.
// Full-K dot per thread (H=512 for h-part, E=256 for x-part); no shared mem.
// hbuf double-buffered: [parity][dir][B][H]; parity = t&1, writes parity^1.
// ---------------------------------------------------------------------------
__global__ __launch_bounds__(256) void enc_step(
    const int* __restrict__ body,
    const float* __restrict__ enc_emb,
    const float* __restrict__ wih_f, const float* __restrict__ whh_f,
    const float* __restrict__ bih_f, const float* __restrict__ bhh_f,
    const float* __restrict__ wih_b, const float* __restrict__ whh_b,
    const float* __restrict__ bih_b, const float* __restrict__ bhh_b,
    float* __restrict__ hbuf,
    int t)
{
    const int p    = t & 1;
    const int bid  = blockIdx.x;
    const int dir  = bid >> 6;
    const int jc   = (bid & 63) * 8;
    const int tid  = threadIdx.x;
    const int b    = tid & 31;
    const int slot = tid >> 5;
    const int j    = jc + slot;

    const float* wih = dir ? wih_b : wih_f;
    const float* whh = dir ? whh_b : whh_f;
    const float* bih = dir ? bih_b : bih_f;
    const float* bhh = dir ? bhh_b : bhh_f;

    const int s   = dir ? (SS - 1 - t) : t;
    const int tok = body[b * SS + s];

    const float* hrow = hbuf + (size_t)((p * 2 + dir) * BB + b) * HH;
    const float* xrow = enc_emb + (size_t)tok * EE;
    const float* wr_h = whh + (size_t)j            * HH;
    const float* wz_h = whh + (size_t)(j + HH)     * HH;
    const float* wn_h = whh + (size_t)(j + 2 * HH) * HH;
    const float* wr_i = wih + (size_t)j            * EE;
    const float* wz_i = wih + (size_t)(j + HH)     * EE;
    const float* wn_i = wih + (size_t)(j + 2 * HH) * EE;

    float pr  = bih[j]          + bhh[j];
    float pz  = bih[j + HH]     + bhh[j + HH];
    float pin = bih[j + 2 * HH];
    float phn = bhh[j + 2 * HH];

    #pragma unroll 4
    for (int k = 0; k < HH; k += 4) {
        float4 h4 = ldf4(hrow + k);
        pr  += dot4(h4, ldf4(wr_h + k));
        pz  += dot4(h4, ldf4(wz_h + k));
        phn += dot4(h4, ldf4(wn_h + k));
    }
    #pragma unroll 4
    for (int k = 0; k < EE; k += 4) {
        float4 x4 = ldf4(xrow + k);
        pr  += dot4(x4, ldf4(wr_i + k));
        pz  += dot4(x4, ldf4(wz_i + k));
        pin += dot4(x4, ldf4(wn_i + k));
    }

    float r = sigmoidf_(pr);
    float z = sigmoidf_(pz);
    float n = tanhf(pin + r * phn);
    float hold = hrow[j];
    hbuf[(size_t)(((p ^ 1) * 2 + dir) * BB + b) * HH + j] =
        (1.0f - z) * n + z * hold;
}

// hidden = h_fwd + h_bwd (final states live at parity 0 after 512 steps)
__global__ __launch_bounds__(256) void enc_fin(
    const float* __restrict__ hbuf, float* __restrict__ hidden)
{
    const int i = blockIdx.x * 256 + threadIdx.x;   // 0 .. B*H-1
    hidden[i] = hbuf[i] + hbuf[BB * HH + i];        // dir0 + dir1 at parity 0
}

// ---------------------------------------------------------------------------
// Decoder h-update. grid = 64 blocks x 256 threads; j = bid*8 + slot.
// ---------------------------------------------------------------------------
__global__ __launch_bounds__(256) void dec_h(
    const float* __restrict__ dec_emb,
    const float* __restrict__ wih, const float* __restrict__ whh,
    const float* __restrict__ bih, const float* __restrict__ bhh,
    const float* __restrict__ hcur, float* __restrict__ hnew,
    const int* __restrict__ tok, int t)
{
    const int tid  = threadIdx.x;
    const int b    = tid & 31;
    const int slot = tid >> 5;
    const int j    = blockIdx.x * 8 + slot;

    const int tk = (t == 0) ? 1 : tok[b];   // BOS = 1
    const float* xrow = dec_emb + (size_t)tk * EE;
    const float* hrow = hcur + (size_t)b * HH;
    const float* wr_h = whh + (size_t)j            * HH;
    const float* wz_h = whh + (size_t)(j + HH)     * HH;
    const float* wn_h = whh + (size_t)(j + 2 * HH) * HH;
    const float* wr_i = wih + (size_t)j            * EE;
    const float* wz_i = wih + (size_t)(j + HH)     * EE;
    const float* wn_i = wih + (size_t)(j + 2 * HH) * EE;

    float pr  = bih[j]          + bhh[j];
    float pz  = bih[j + HH]     + bhh[j + HH];
    float pin = bih[j + 2 * HH];
    float phn = bhh[j + 2 * HH];

    #pragma unroll 4
    for (int k = 0; k < HH; k += 4) {
        float4 h4 = ldf4(hrow + k);
        pr  += dot4(h4, ldf4(wr_h + k));
        pz  += dot4(h4, ldf4(wz_h + k));
        phn += dot4(h4, ldf4(wn_h + k));
    }
    #pragma unroll 4
    for (int k = 0; k < EE; k += 4) {
        float4 x4 = ldf4(xrow + k);
        pr  += dot4(x4, ldf4(wr_i + k));
        pz  += dot4(x4, ldf4(wz_i + k));
        pin += dot4(x4, ldf4(wn_i + k));
    }

    float r = sigmoidf_(pr);
    float z = sigmoidf_(pz);
    float n = tanhf(pin + r * phn);
    float hold = hrow[j];
    hnew[(size_t)b * HH + j] = (1.0f - z) * n + z * hold;
}

// ---------------------------------------------------------------------------
// Logits + per-chunk argmax candidates. grid = 500 blocks x 256 threads.
// Block c handles v in [c*64, c*64+64); thread (b=tid&31, vg=tid>>5) does 8 v.
// Stores logits to out[b][t][v] and packed (value,index) key to cand[c][b].
// ---------------------------------------------------------------------------
__global__ __launch_bounds__(256) void dec_logits(
    const float* __restrict__ fc_w, const float* __restrict__ fc_b,
    const float* __restrict__ h,
    unsigned long long* __restrict__ cand,
    float* __restrict__ out, int t)
{
    const int c  = blockIdx.x;
    const int tid = threadIdx.x;
    const int b  = tid & 31;
    const int vg = tid >> 5;
    const int v0 = c * 64 + vg * 8;

    __shared__ unsigned long long lred[8][32];

    float acc[8];
    #pragma unroll
    for (int i = 0; i < 8; ++i) acc[i] = 0.f;

    const float* hrow = h + (size_t)b * HH;
    const float* w0   = fc_w + (size_t)v0 * HH;
    for (int k = 0; k < HH; k += 4) {
        float4 h4 = ldf4(hrow + k);
        #pragma unroll
        for (int i = 0; i < 8; ++i)
            acc[i] += dot4(h4, ldf4(w0 + (size_t)i * HH + k));
    }
    #pragma unroll
    for (int i = 0; i < 8; ++i) acc[i] += fc_b[v0 + i];

    float* op = out + ((size_t)(b * TT + t)) * VV + v0;
    *reinterpret_cast<float4*>(op)     = make_float4(acc[0], acc[1], acc[2], acc[3]);
    *reinterpret_cast<float4*>(op + 4) = make_float4(acc[4], acc[5], acc[6], acc[7]);

    float best = acc[0]; int bestv = v0;
    #pragma unroll
    for (int i = 1; i < 8; ++i)
        if (acc[i] > best) { best = acc[i]; bestv = v0 + i; }
    unsigned u = __float_as_uint(best);
    u = (u >> 31) ? ~u : (u | 0x80000000u);
    unsigned long long key =
        ((unsigned long long)u << 32) | (0xFFFFFFFFu - (unsigned)bestv);
    lred[vg][b] = key;
    __syncthreads();
    if (tid < 32) {
        unsigned long long km = lred[0][tid];
        #pragma unroll
        for (int g2 = 1; g2 < 8; ++g2) {
            unsigned long long k2 = lred[g2][tid];
            if (k2 > km) km = k2;
        }
        cand[(size_t)c * 32 + tid] = km;
    }
}

// ---------------------------------------------------------------------------
// Final argmax: reduce 500 chunk candidates -> tok[b]. grid = 32 x 256.
// ---------------------------------------------------------------------------
__global__ __launch_bounds__(256) void dec_argmax(
    const unsigned long long* __restrict__ cand, int* __restrict__ tok)
{
    const int b  = blockIdx.x;
    const int tid = threadIdx.x;
    __shared__ unsigned long long wred[4];

    unsigned long long km = 0ull;
    for (int c = tid; c < 500; c += 256) {
        unsigned long long k2 = cand[(size_t)c * 32 + b];
        if (k2 > km) km = k2;
    }
    for (int off = 32; off > 0; off >>= 1) {
        unsigned hi = (unsigned)(km >> 32), lo = (unsigned)km;
        unsigned ohi = __shfl_down(hi, off);
        unsigned olo = __shfl_down(lo, off);
        unsigned long long o = ((unsigned long long)ohi << 32) | olo;
        if (o > km) km = o;
    }
    if ((tid & 63) == 0) wred[tid >> 6] = km;
    __syncthreads();
    if (tid == 0) {
        km = wred[0];
        #pragma unroll
        for (int w = 1; w < 4; ++w)
            if (wred[w] > km) km = wred[w];
        tok[b] = (int)(0xFFFFFFFFu - (unsigned)(km & 0xFFFFFFFFull));
    }
}

// ---------------------------------------------------------------------------
extern "C" void kernel_launch(void* const* d_in, const int* in_sizes, int n_in,
                              void* d_out, int out_size, void* d_ws, size_t ws_size,
                              hipStream_t stream) {
    (void)in_sizes; (void)n_in; (void)out_size; (void)ws_size;

    const int*   body    = (const int*)  d_in[0];
    const float* enc_emb = (const float*)d_in[2];
    const float* wih_f   = (const float*)d_in[3];
    const float* whh_f   = (const float*)d_in[4];
    const float* bih_f   = (const float*)d_in[5];
    const float* bhh_f   = (const float*)d_in[6];
    const float* wih_b   = (const float*)d_in[7];
    const float* whh_b   = (const float*)d_in[8];
    const float* bih_b   = (const float*)d_in[9];
    const float* bhh_b   = (const float*)d_in[10];
    const float* dec_emb = (const float*)d_in[11];
    const float* dwih    = (const float*)d_in[12];
    const float* dwhh    = (const float*)d_in[13];
    const float* dbih    = (const float*)d_in[14];
    const float* dbhh    = (const float*)d_in[15];
    const float* fc_w    = (const float*)d_in[16];
    const float* fc_b    = (const float*)d_in[17];
    float* out = (float*)d_out;

    char* ws = (char*)d_ws;
    float* hbuf   = (float*)(ws);                 // [2][2][32][512] = 262144 B
    float* hidden = (float*)(ws + 262144);        // 65536 B
    float* hA     = (float*)(ws + 327680);        // 65536 B
    float* hB     = (float*)(ws + 393216);        // 65536 B
    unsigned long long* cand =
        (unsigned long long*)(ws + 458752);       // 500*32*8 = 128000 B
    int* tok = (int*)(ws + 586752);               // 128 B

    // zero parity-0 h for both dirs: first 2*B*H floats = 131072 bytes
    hipMemsetAsync(hbuf, 0, (size_t)2 * BB * HH * sizeof(float), stream);

    for (int t = 0; t < SS; ++t) {
        enc_step<<<128, 256, 0, stream>>>(
            body, enc_emb, wih_f, whh_f, bih_f, bhh_f,
            wih_b, whh_b, bih_b, bhh_b, hbuf, t);
    }
    enc_fin<<<64, 256, 0, stream>>>(hbuf, hidden);

    for (int t = 0; t < TT; ++t) {
        const float* hc = (t == 0) ? hidden : ((t & 1) ? hA : hB);
        float*       hn = (t & 1) ? hB : hA;
        dec_h<<<64, 256, 0, stream>>>(dec_emb, dwih, dwhh, dbih, dbhh,
                                      hc, hn, tok, t);
        dec_logits<<<500, 256, 0, stream>>>(fc_w, fc_b, hn, cand, out, t);
        if (t < TT - 1)
            dec_argmax<<<32, 256, 0, stream>>>(cand, tok);
    }
}

// Round 3
// 14478.998 us; speedup vs baseline: 2.0318x; 2.0318x over previous
//
#include <hip/hip_runtime.h>
#include <math.h>

#define BB 32
#define SS 512
#define EE 256
#define HH 512
#define VV 32000
#define TT 30

__device__ __forceinline__ float4 ldf4(const float* p) {
    return *reinterpret_cast<const float4*>(p);
}
__device__ __forceinline__ float dot4(float4 a, float4 b) {
    return a.x * b.x + a.y * b.y + a.z * b.z + a.w * b.w;
}
__device__ __forceinline__ float sigmoidf_(float x) {
    return 1.0f / (1.0f + expf(-x));
}

// ---------------------------------------------------------------------------
// Encoder single step, v2. grid = 512 blocks x 256 threads.
//   bid>>8 = dir; (bid&255) = j-pair index (j = jp*2 + jj).
//   thread: b = tid&31, kq = (tid>>5)&3 (K quarter), jj = tid>>7.
// Each thread computes a K-quarter partial of (r,z,hn,in) for its (b,j);
// 3-stage LDS combine; 64 threads finalize the GRU nonlinearity.
// 2048 waves total -> 8 waves/CU (2/SIMD); per-block weight rows = 18.4 KB
// -> per-XCD steady weight working set ~1.2 MB (L2-resident).
// ---------------------------------------------------------------------------
__global__ __launch_bounds__(256) void enc_step2(
    const int* __restrict__ body,
    const float* __restrict__ enc_emb,
    const float* __restrict__ wih_f, const float* __restrict__ whh_f,
    const float* __restrict__ bih_f, const float* __restrict__ bhh_f,
    const float* __restrict__ wih_b, const float* __restrict__ whh_b,
    const float* __restrict__ bih_b, const float* __restrict__ bhh_b,
    float* __restrict__ hbuf,    // [2][2][B][H]
    int t)
{
    const int bid = blockIdx.x;
    const int dir = bid >> 8;
    const int jp  = bid & 255;
    const int tid = threadIdx.x;
    const int b   = tid & 31;
    const int kq  = (tid >> 5) & 3;
    const int jj  = tid >> 7;
    const int j   = jp * 2 + jj;

    const float* wih = dir ? wih_b : wih_f;
    const float* whh = dir ? whh_b : whh_f;

    const int s   = dir ? (SS - 1 - t) : t;
    const int p   = t & 1;
    const int tok = body[b * SS + s];

    const float* hrow = hbuf + (size_t)((p * 2 + dir) * BB + b) * HH;
    const float* xrow = enc_emb + (size_t)tok * EE;
    const float* wr_h = whh + (size_t)j            * HH;
    const float* wz_h = whh + (size_t)(j + HH)     * HH;
    const float* wn_h = whh + (size_t)(j + 2 * HH) * HH;
    const float* wr_i = wih + (size_t)j            * EE;
    const float* wz_i = wih + (size_t)(j + HH)     * EE;
    const float* wn_i = wih + (size_t)(j + 2 * HH) * EE;

    float pr = 0.f, pz = 0.f, phn = 0.f, pin = 0.f;

    const int kh = kq * 128;            // h-segment [kh, kh+128)
    #pragma unroll 8
    for (int k = kh; k < kh + 128; k += 4) {
        float4 h4 = ldf4(hrow + k);
        pr  += dot4(h4, ldf4(wr_h + k));
        pz  += dot4(h4, ldf4(wz_h + k));
        phn += dot4(h4, ldf4(wn_h + k));
    }
    const int ke = kq * 64;             // x-segment [ke, ke+64)
    #pragma unroll 8
    for (int k = ke; k < ke + 64; k += 4) {
        float4 x4 = ldf4(xrow + k);
        pr  += dot4(x4, ldf4(wr_i + k));
        pz  += dot4(x4, ldf4(wz_i + k));
        pin += dot4(x4, ldf4(wn_i + k));
    }

    __shared__ float part[4][64][4];
    __shared__ float gsum[64][4];
    const int slot = jj * 32 + b;
    part[kq][slot][0] = pr;
    part[kq][slot][1] = pz;
    part[kq][slot][2] = phn;
    part[kq][slot][3] = pin;
    __syncthreads();

    {
        const int sl = tid >> 2, a = tid & 3;
        gsum[sl][a] = part[0][sl][a] + part[1][sl][a]
                    + part[2][sl][a] + part[3][sl][a];
    }
    __syncthreads();

    if (tid < 64) {
        const int b2  = tid & 31;
        const int jj2 = tid >> 5;
        const int j2  = jp * 2 + jj2;
        const float* bihp = dir ? bih_b : bih_f;
        const float* bhhp = dir ? bhh_b : bhh_f;
        float spr  = gsum[tid][0] + bihp[j2]          + bhhp[j2];
        float spz  = gsum[tid][1] + bihp[j2 + HH]     + bhhp[j2 + HH];
        float sphn = gsum[tid][2] + bhhp[j2 + 2 * HH];
        float spin = gsum[tid][3] + bihp[j2 + 2 * HH];
        float r = sigmoidf_(spr);
        float z = sigmoidf_(spz);
        float n = tanhf(spin + r * sphn);
        float hold = hbuf[(size_t)((p * 2 + dir) * BB + b2) * HH + j2];
        hbuf[(size_t)(((p ^ 1) * 2 + dir) * BB + b2) * HH + j2] =
            (1.0f - z) * n + z * hold;
    }
}

// hidden = h_fwd + h_bwd (final states live at parity 0 after 512 steps)
__global__ __launch_bounds__(256) void enc_fin(
    const float* __restrict__ hbuf, float* __restrict__ hidden)
{
    const int i = blockIdx.x * 256 + threadIdx.x;   // 0 .. B*H-1
    hidden[i] = hbuf[i] + hbuf[BB * HH + i];        // dir0 + dir1 at parity 0
}

// ---------------------------------------------------------------------------
// Decoder h-update, v2 (same structure as enc_step2, one direction).
// grid = 256 blocks x 256 threads; bid = j-pair.
// ---------------------------------------------------------------------------
__global__ __launch_bounds__(256) void dec_h2(
    const float* __restrict__ dec_emb,
    const float* __restrict__ wih, const float* __restrict__ whh,
    const float* __restrict__ bih, const float* __restrict__ bhh,
    const float* __restrict__ hcur, float* __restrict__ hnew,
    const int* __restrict__ tok, int t)
{
    const int jp  = blockIdx.x;
    const int tid = threadIdx.x;
    const int b   = tid & 31;
    const int kq  = (tid >> 5) & 3;
    const int jj  = tid >> 7;
    const int j   = jp * 2 + jj;

    const int tk = (t == 0) ? 1 : tok[b];   // BOS = 1
    const float* xrow = dec_emb + (size_t)tk * EE;
    const float* hrow = hcur + (size_t)b * HH;
    const float* wr_h = whh + (size_t)j            * HH;
    const float* wz_h = whh + (size_t)(j + HH)     * HH;
    const float* wn_h = whh + (size_t)(j + 2 * HH) * HH;
    const float* wr_i = wih + (size_t)j            * EE;
    const float* wz_i = wih + (size_t)(j + HH)     * EE;
    const float* wn_i = wih + (size_t)(j + 2 * HH) * EE;

    float pr = 0.f, pz = 0.f, phn = 0.f, pin = 0.f;

    const int kh = kq * 128;
    #pragma unroll 8
    for (int k = kh; k < kh + 128; k += 4) {
        float4 h4 = ldf4(hrow + k);
        pr  += dot4(h4, ldf4(wr_h + k));
        pz  += dot4(h4, ldf4(wz_h + k));
        phn += dot4(h4, ldf4(wn_h + k));
    }
    const int ke = kq * 64;
    #pragma unroll 8
    for (int k = ke; k < ke + 64; k += 4) {
        float4 x4 = ldf4(xrow + k);
        pr  += dot4(x4, ldf4(wr_i + k));
        pz  += dot4(x4, ldf4(wz_i + k));
        pin += dot4(x4, ldf4(wn_i + k));
    }

    __shared__ float part[4][64][4];
    __shared__ float gsum[64][4];
    const int slot = jj * 32 + b;
    part[kq][slot][0] = pr;
    part[kq][slot][1] = pz;
    part[kq][slot][2] = phn;
    part[kq][slot][3] = pin;
    __syncthreads();

    {
        const int sl = tid >> 2, a = tid & 3;
        gsum[sl][a] = part[0][sl][a] + part[1][sl][a]
                    + part[2][sl][a] + part[3][sl][a];
    }
    __syncthreads();

    if (tid < 64) {
        const int b2  = tid & 31;
        const int jj2 = tid >> 5;
        const int j2  = jp * 2 + jj2;
        float spr  = gsum[tid][0] + bih[j2]          + bhh[j2];
        float spz  = gsum[tid][1] + bih[j2 + HH]     + bhh[j2 + HH];
        float sphn = gsum[tid][2] + bhh[j2 + 2 * HH];
        float spin = gsum[tid][3] + bih[j2 + 2 * HH];
        float r = sigmoidf_(spr);
        float z = sigmoidf_(spz);
        float n = tanhf(spin + r * sphn);
        float hold = hcur[(size_t)b2 * HH + j2];
        hnew[(size_t)b2 * HH + j2] = (1.0f - z) * n + z * hold;
    }
}

// ---------------------------------------------------------------------------
// Logits + per-chunk argmax candidates. grid = 500 blocks x 256 threads.
// (unchanged from round 2)
// ---------------------------------------------------------------------------
__global__ __launch_bounds__(256) void dec_logits(
    const float* __restrict__ fc_w, const float* __restrict__ fc_b,
    const float* __restrict__ h,
    unsigned long long* __restrict__ cand,
    float* __restrict__ out, int t)
{
    const int c  = blockIdx.x;
    const int tid = threadIdx.x;
    const int b  = tid & 31;
    const int vg = tid >> 5;
    const int v0 = c * 64 + vg * 8;

    __shared__ unsigned long long lred[8][32];

    float acc[8];
    #pragma unroll
    for (int i = 0; i < 8; ++i) acc[i] = 0.f;

    const float* hrow = h + (size_t)b * HH;
    const float* w0   = fc_w + (size_t)v0 * HH;
    for (int k = 0; k < HH; k += 4) {
        float4 h4 = ldf4(hrow + k);
        #pragma unroll
        for (int i = 0; i < 8; ++i)
            acc[i] += dot4(h4, ldf4(w0 + (size_t)i * HH + k));
    }
    #pragma unroll
    for (int i = 0; i < 8; ++i) acc[i] += fc_b[v0 + i];

    float* op = out + ((size_t)(b * TT + t)) * VV + v0;
    *reinterpret_cast<float4*>(op)     = make_float4(acc[0], acc[1], acc[2], acc[3]);
    *reinterpret_cast<float4*>(op + 4) = make_float4(acc[4], acc[5], acc[6], acc[7]);

    float best = acc[0]; int bestv = v0;
    #pragma unroll
    for (int i = 1; i < 8; ++i)
        if (acc[i] > best) { best = acc[i]; bestv = v0 + i; }
    unsigned u = __float_as_uint(best);
    u = (u >> 31) ? ~u : (u | 0x80000000u);
    unsigned long long key =
        ((unsigned long long)u << 32) | (0xFFFFFFFFu - (unsigned)bestv);
    lred[vg][b] = key;
    __syncthreads();
    if (tid < 32) {
        unsigned long long km = lred[0][tid];
        #pragma unroll
        for (int g2 = 1; g2 < 8; ++g2) {
            unsigned long long k2 = lred[g2][tid];
            if (k2 > km) km = k2;
        }
        cand[(size_t)c * 32 + tid] = km;
    }
}

// ---------------------------------------------------------------------------
// Final argmax: reduce 500 chunk candidates -> tok[b]. grid = 32 x 256.
// ---------------------------------------------------------------------------
__global__ __launch_bounds__(256) void dec_argmax(
    const unsigned long long* __restrict__ cand, int* __restrict__ tok)
{
    const int b  = blockIdx.x;
    const int tid = threadIdx.x;
    __shared__ unsigned long long wred[4];

    unsigned long long km = 0ull;
    for (int c = tid; c < 500; c += 256) {
        unsigned long long k2 = cand[(size_t)c * 32 + b];
        if (k2 > km) km = k2;
    }
    for (int off = 32; off > 0; off >>= 1) {
        unsigned hi = (unsigned)(km >> 32), lo = (unsigned)km;
        unsigned ohi = __shfl_down(hi, off);
        unsigned olo = __shfl_down(lo, off);
        unsigned long long o = ((unsigned long long)ohi << 32) | olo;
        if (o > km) km = o;
    }
    if ((tid & 63) == 0) wred[tid >> 6] = km;
    __syncthreads();
    if (tid == 0) {
        km = wred[0];
        #pragma unroll
        for (int w = 1; w < 4; ++w)
            if (wred[w] > km) km = wred[w];
        tok[b] = (int)(0xFFFFFFFFu - (unsigned)(km & 0xFFFFFFFFull));
    }
}

// ---------------------------------------------------------------------------
extern "C" void kernel_launch(void* const* d_in, const int* in_sizes, int n_in,
                              void* d_out, int out_size, void* d_ws, size_t ws_size,
                              hipStream_t stream) {
    (void)in_sizes; (void)n_in; (void)out_size; (void)ws_size;

    const int*   body    = (const int*)  d_in[0];
    const float* enc_emb = (const float*)d_in[2];
    const float* wih_f   = (const float*)d_in[3];
    const float* whh_f   = (const float*)d_in[4];
    const float* bih_f   = (const float*)d_in[5];
    const float* bhh_f   = (const float*)d_in[6];
    const float* wih_b   = (const float*)d_in[7];
    const float* whh_b   = (const float*)d_in[8];
    const float* bih_b   = (const float*)d_in[9];
    const float* bhh_b   = (const float*)d_in[10];
    const float* dec_emb = (const float*)d_in[11];
    const float* dwih    = (const float*)d_in[12];
    const float* dwhh    = (const float*)d_in[13];
    const float* dbih    = (const float*)d_in[14];
    const float* dbhh    = (const float*)d_in[15];
    const float* fc_w    = (const float*)d_in[16];
    const float* fc_b    = (const float*)d_in[17];
    float* out = (float*)d_out;

    char* ws = (char*)d_ws;
    float* hbuf   = (float*)(ws);                 // [2][2][32][512] = 262144 B
    float* hidden = (float*)(ws + 262144);        // 65536 B
    float* hA     = (float*)(ws + 327680);        // 65536 B
    float* hB     = (float*)(ws + 393216);        // 65536 B
    unsigned long long* cand =
        (unsigned long long*)(ws + 458752);       // 500*32*8 = 128000 B
    int* tok = (int*)(ws + 586752);               // 128 B

    // zero parity-0 h for both dirs
    hipMemsetAsync(hbuf, 0, (size_t)2 * BB * HH * sizeof(float), stream);

    for (int t = 0; t < SS; ++t) {
        enc_step2<<<512, 256, 0, stream>>>(
            body, enc_emb, wih_f, whh_f, bih_f, bhh_f,
            wih_b, whh_b, bih_b, bhh_b, hbuf, t);
    }
    enc_fin<<<64, 256, 0, stream>>>(hbuf, hidden);

    for (int t = 0; t < TT; ++t) {
        const float* hc = (t == 0) ? hidden : ((t & 1) ? hA : hB);
        float*       hn = (t & 1) ? hB : hA;
        dec_h2<<<256, 256, 0, stream>>>(dec_emb, dwih, dwhh, dbih, dbhh,
                                        hc, hn, tok, t);
        dec_logits<<<500, 256, 0, stream>>>(fc_w, fc_b, hn, cand, out, t);
        if (t < TT - 1)
            dec_argmax<<<32, 256, 0, stream>>>(cand, tok);
    }
}

// Round 4
// 14455.280 us; speedup vs baseline: 2.0351x; 1.0016x over previous
//
#include <hip/hip_runtime.h>
#include <math.h>

#define BB 32
#define SS 512
#define EE 256
#define HH 512
#define VV 32000
#define TT 30
#define WP 776   // LDS weight row pitch: 768 data + 8 pad (bank spread, 16B aligned)

__device__ __forceinline__ float4 ldf4(const float* p) {
    return *reinterpret_cast<const float4*>(p);
}
__device__ __forceinline__ float sigmoidf_(float x) {
    return 1.0f / (1.0f + expf(-x));
}
__device__ __forceinline__ void fma4(float4& a, float s, const float4& b) {
    a.x = fmaf(s, b.x, a.x); a.y = fmaf(s, b.y, a.y);
    a.z = fmaf(s, b.z, a.z); a.w = fmaf(s, b.w, a.w);
}

// ---------------------------------------------------------------------------
// Persistent encoder. grid = 256 x 256 (1 block/CU, all co-resident).
// block: dir = bid>>7, jc = bid&127 -> owns j in [jc*4, jc*4+4).
// Weights for its 4 j live in LDS (loaded once, zero duplication device-wide).
// h stored TRANSPOSED in global: hbufT[parity][dir][k 512][b 32].
// Per step: stage x (transposed, LDS); each thread (ks,jl,bq) accumulates
// b-quad float4 partials over its k-range; LDS reduce over ks; 128 threads
// finalize GRU nonlinearity and store h_new (coalesced).
// Cross-block sync: per-dir monotonic counter, release-add / relaxed-spin +
// acquire fence (agent scope).
// ---------------------------------------------------------------------------
__global__ __launch_bounds__(256) void enc_persist(
    const int* __restrict__ body,
    const float* __restrict__ enc_emb,
    const float* __restrict__ wih_f, const float* __restrict__ whh_f,
    const float* __restrict__ bih_f, const float* __restrict__ bhh_f,
    const float* __restrict__ wih_b, const float* __restrict__ whh_b,
    const float* __restrict__ bih_b, const float* __restrict__ bhh_b,
    float* __restrict__ hbufT,          // [2][2][512][32]
    unsigned int* __restrict__ ctr)     // [2] padded: ctr[0], ctr[32]
{
    const int bid = blockIdx.x;
    const int dir = bid >> 7;
    const int jc  = bid & 127;
    const int tid = threadIdx.x;

    const float* wih = dir ? wih_b : wih_f;
    const float* whh = dir ? whh_b : whh_f;
    const float* bih = dir ? bih_b : bih_f;
    const float* bhh = dir ? bhh_b : bhh_f;

    __shared__ float wlds[4 * 3 * WP];   // 37,248 B
    __shared__ float xlds[EE * BB];      // 32,768 B  [k][b]
    __shared__ float part[16][256];      // 16,384 B  [i*4+type][tid]
    __shared__ float blds[4][4];

    // ---- load weights into LDS once: 4j x 3g x 768k ----
    for (int idx = tid; idx < 2304; idx += 256) {
        const int j   = idx / 576;
        const int rem = idx - j * 576;
        const int g   = rem / 192;
        const int k   = (rem - g * 192) * 4;
        const int row = g * HH + (jc * 4 + j);
        float4 v;
        if (k < HH) v = ldf4(whh + (size_t)row * HH + k);
        else        v = ldf4(wih + (size_t)row * EE + (k - HH));
        float* dst = wlds + (j * 3 + g) * WP + k;
        dst[0] = v.x; dst[1] = v.y; dst[2] = v.z; dst[3] = v.w;
    }
    if (tid < 4) {
        const int jg = jc * 4 + tid;
        blds[tid][0] = bih[jg] + bhh[jg];
        blds[tid][1] = bih[jg + HH] + bhh[jg + HH];
        blds[tid][2] = bih[jg + 2 * HH];   // b_in
        blds[tid][3] = bhh[jg + 2 * HH];   // b_hn
    }
    __syncthreads();

    const int ks = tid >> 5;         // 0..7  k-split
    const int jl = (tid >> 3) & 3;   // 0..3  local j
    const int bq = tid & 7;          // 0..7  b-quad
    const int sb = tid & 31;         // staging: b
    const int kc = tid >> 5;         // staging: k-chunk

    unsigned int* myctr = ctr + dir * 32;
    const float* wj = wlds + jl * 3 * WP;

    for (int t = 0; t < SS; ++t) {
        const int p = t & 1;

        if (t > 0) {
            if (tid == 0) {
                const unsigned tgt = (unsigned)(128 * t);
                while (__hip_atomic_load(myctr, __ATOMIC_RELAXED,
                                         __HIP_MEMORY_SCOPE_AGENT) < tgt)
                    __builtin_amdgcn_s_sleep(1);
            }
            __syncthreads();
            __builtin_amdgcn_fence(__ATOMIC_ACQUIRE, "agent");
        }

        // ---- stage x transposed into LDS ----
        {
            const int s    = dir ? (SS - 1 - t) : t;
            const int tokb = body[sb * SS + s];
            const float* xr = enc_emb + (size_t)tokb * EE + kc * 32;
            #pragma unroll
            for (int i = 0; i < 8; ++i) {
                float4 v = ldf4(xr + i * 4);
                const int k = kc * 32 + i * 4;
                xlds[(k + 0) * BB + sb] = v.x;
                xlds[(k + 1) * BB + sb] = v.y;
                xlds[(k + 2) * BB + sb] = v.z;
                xlds[(k + 3) * BB + sb] = v.w;
            }
        }
        __syncthreads();

        // ---- compute b-quad partials ----
        const float* hb = hbufT + (size_t)(p * 2 + dir) * HH * BB;
        float4 aR  = {0,0,0,0}, aZ = {0,0,0,0};
        float4 aHN = {0,0,0,0}, aIN = {0,0,0,0};

        const int k0 = ks * 64;
        #pragma unroll 4
        for (int kk = 0; kk < 64; kk += 4) {
            const int k = k0 + kk;
            float4 h0 = ldf4(hb + (k + 0) * BB + bq * 4);
            float4 h1 = ldf4(hb + (k + 1) * BB + bq * 4);
            float4 h2 = ldf4(hb + (k + 2) * BB + bq * 4);
            float4 h3 = ldf4(hb + (k + 3) * BB + bq * 4);
            float4 wr = ldf4(wj + 0 * WP + k);
            float4 wz = ldf4(wj + 1 * WP + k);
            float4 wn = ldf4(wj + 2 * WP + k);
            fma4(aR, wr.x, h0);  fma4(aR, wr.y, h1);  fma4(aR, wr.z, h2);  fma4(aR, wr.w, h3);
            fma4(aZ, wz.x, h0);  fma4(aZ, wz.y, h1);  fma4(aZ, wz.z, h2);  fma4(aZ, wz.w, h3);
            fma4(aHN, wn.x, h0); fma4(aHN, wn.y, h1); fma4(aHN, wn.z, h2); fma4(aHN, wn.w, h3);
        }
        const int kx0 = ks * 32;
        #pragma unroll 4
        for (int kk = 0; kk < 32; kk += 4) {
            const int k = kx0 + kk;
            float4 x0 = ldf4(xlds + (k + 0) * BB + bq * 4);
            float4 x1 = ldf4(xlds + (k + 1) * BB + bq * 4);
            float4 x2 = ldf4(xlds + (k + 2) * BB + bq * 4);
            float4 x3 = ldf4(xlds + (k + 3) * BB + bq * 4);
            float4 wr = ldf4(wj + 0 * WP + HH + k);
            float4 wz = ldf4(wj + 1 * WP + HH + k);
            float4 wn = ldf4(wj + 2 * WP + HH + k);
            fma4(aR, wr.x, x0);  fma4(aR, wr.y, x1);  fma4(aR, wr.z, x2);  fma4(aR, wr.w, x3);
            fma4(aZ, wz.x, x0);  fma4(aZ, wz.y, x1);  fma4(aZ, wz.z, x2);  fma4(aZ, wz.w, x3);
            fma4(aIN, wn.x, x0); fma4(aIN, wn.y, x1); fma4(aIN, wn.z, x2); fma4(aIN, wn.w, x3);
        }

        // ---- partials to LDS: part[i*4+type][tid] ----
        part[ 0][tid] = aR.x;  part[ 4][tid] = aR.y;  part[ 8][tid] = aR.z;  part[12][tid] = aR.w;
        part[ 1][tid] = aZ.x;  part[ 5][tid] = aZ.y;  part[ 9][tid] = aZ.z;  part[13][tid] = aZ.w;
        part[ 2][tid] = aHN.x; part[ 6][tid] = aHN.y; part[10][tid] = aHN.z; part[14][tid] = aHN.w;
        part[ 3][tid] = aIN.x; part[ 7][tid] = aIN.y; part[11][tid] = aIN.z; part[15][tid] = aIN.w;
        __syncthreads();

        // ---- finalize: 128 threads, one (j,b) each ----
        if (tid < 128) {
            const int j2 = tid >> 5, b = tid & 31;
            const int base = j2 * 8 + (b >> 2);
            const int i2 = b & 3;
            float sR = 0.f, sZ = 0.f, sHN = 0.f, sIN = 0.f;
            #pragma unroll
            for (int q = 0; q < 8; ++q) {
                const int src = q * 32 + base;
                sR  += part[i2 * 4 + 0][src];
                sZ  += part[i2 * 4 + 1][src];
                sHN += part[i2 * 4 + 2][src];
                sIN += part[i2 * 4 + 3][src];
            }
            sR += blds[j2][0]; sZ += blds[j2][1];
            sIN += blds[j2][2]; sHN += blds[j2][3];
            const float r = sigmoidf_(sR);
            const float z = sigmoidf_(sZ);
            const float n = tanhf(sIN + r * sHN);
            const int jg = jc * 4 + j2;
            const float hold = hbufT[(size_t)(p * 2 + dir) * HH * BB + jg * BB + b];
            hbufT[(size_t)((p ^ 1) * 2 + dir) * HH * BB + jg * BB + b] =
                (1.0f - z) * n + z * hold;
        }
        __syncthreads();   // drains vmcnt -> all waves' h stores are in L2
        if (tid == 0)
            __hip_atomic_fetch_add(myctr, 1u, __ATOMIC_RELEASE,
                                   __HIP_MEMORY_SCOPE_AGENT);
    }
}

// hidden(T) for decoder: hdT[j][b] = hf + hb  (parity 0 after 512 steps)
__global__ __launch_bounds__(256) void enc_fin(
    const float* __restrict__ hbufT, float* __restrict__ hdT)
{
    const int i = blockIdx.x * 256 + threadIdx.x;   // 0 .. 512*32-1
    hdT[i] = hbufT[i] + hbufT[HH * BB + i];
}

// ---------------------------------------------------------------------------
// Persistent decoder. grid = 256 x 256. 30 steps x 3 phases, grid-wide
// barrier between phases (single monotonic counter, 256 arrivals/phase).
// Phase A (blocks 0..127): GRU h-update, encoder-identical structure,
//   writes hdT[p^1] (transposed) + hdrow (row-major, for phase B).
// Phase B (all blocks): logits chunks of 64 v (c = bid, bid+256), store to
//   out + per-chunk argmax candidate keys.
// Phase C (blocks 0..31): reduce 500 candidates -> tok[b].
// ---------------------------------------------------------------------------
__global__ __launch_bounds__(256) void dec_persist(
    const float* __restrict__ dec_emb,
    const float* __restrict__ wih, const float* __restrict__ whh,
    const float* __restrict__ bih, const float* __restrict__ bhh,
    const float* __restrict__ fc_w, const float* __restrict__ fc_b,
    float* __restrict__ hdT,                 // [2][512][32]
    float* __restrict__ hdrow,               // [32][512]
    unsigned long long* __restrict__ cand,   // [500][32]
    int* __restrict__ tok,                   // [32]
    float* __restrict__ out,                 // [32][30][32000]
    unsigned int* __restrict__ ctr)
{
    const int bid = blockIdx.x;
    const int tid = threadIdx.x;
    const int jc  = bid;   // valid for bid<128

    __shared__ float wlds[4 * 3 * WP];
    __shared__ float xlds[EE * BB];
    __shared__ float part[16][256];
    __shared__ float blds[4][4];
    __shared__ unsigned long long lred[8][32];

    if (bid < 128) {
        for (int idx = tid; idx < 2304; idx += 256) {
            const int j   = idx / 576;
            const int rem = idx - j * 576;
            const int g   = rem / 192;
            const int k   = (rem - g * 192) * 4;
            const int row = g * HH + (jc * 4 + j);
            float4 v;
            if (k < HH) v = ldf4(whh + (size_t)row * HH + k);
            else        v = ldf4(wih + (size_t)row * EE + (k - HH));
            float* dst = wlds + (j * 3 + g) * WP + k;
            dst[0] = v.x; dst[1] = v.y; dst[2] = v.z; dst[3] = v.w;
        }
        if (tid < 4) {
            const int jg = jc * 4 + tid;
            blds[tid][0] = bih[jg] + bhh[jg];
            blds[tid][1] = bih[jg + HH] + bhh[jg + HH];
            blds[tid][2] = bih[jg + 2 * HH];
            blds[tid][3] = bhh[jg + 2 * HH];
        }
    }
    __syncthreads();

    const int ks = tid >> 5;
    const int jl = (tid >> 3) & 3;
    const int bq = tid & 7;
    const int sb = tid & 31;
    const int kc = tid >> 5;
    const float* wj = wlds + jl * 3 * WP;

    unsigned tgt = 0;

    for (int t = 0; t < TT; ++t) {
        const int p = t & 1;

        // ================= Phase A: h-update =================
        if (bid < 128) {
            const int tk = (t == 0) ? 1 : tok[sb];   // BOS = 1
            {
                const float* xr = dec_emb + (size_t)tk * EE + kc * 32;
                #pragma unroll
                for (int i = 0; i < 8; ++i) {
                    float4 v = ldf4(xr + i * 4);
                    const int k = kc * 32 + i * 4;
                    xlds[(k + 0) * BB + sb] = v.x;
                    xlds[(k + 1) * BB + sb] = v.y;
                    xlds[(k + 2) * BB + sb] = v.z;
                    xlds[(k + 3) * BB + sb] = v.w;
                }
            }
            __syncthreads();

            const float* hb = hdT + (size_t)p * HH * BB;
            float4 aR  = {0,0,0,0}, aZ = {0,0,0,0};
            float4 aHN = {0,0,0,0}, aIN = {0,0,0,0};

            const int k0 = ks * 64;
            #pragma unroll 4
            for (int kk = 0; kk < 64; kk += 4) {
                const int k = k0 + kk;
                float4 h0 = ldf4(hb + (k + 0) * BB + bq * 4);
                float4 h1 = ldf4(hb + (k + 1) * BB + bq * 4);
                float4 h2 = ldf4(hb + (k + 2) * BB + bq * 4);
                float4 h3 = ldf4(hb + (k + 3) * BB + bq * 4);
                float4 wr = ldf4(wj + 0 * WP + k);
                float4 wz = ldf4(wj + 1 * WP + k);
                float4 wn = ldf4(wj + 2 * WP + k);
                fma4(aR, wr.x, h0);  fma4(aR, wr.y, h1);  fma4(aR, wr.z, h2);  fma4(aR, wr.w, h3);
                fma4(aZ, wz.x, h0);  fma4(aZ, wz.y, h1);  fma4(aZ, wz.z, h2);  fma4(aZ, wz.w, h3);
                fma4(aHN, wn.x, h0); fma4(aHN, wn.y, h1); fma4(aHN, wn.z, h2); fma4(aHN, wn.w, h3);
            }
            const int kx0 = ks * 32;
            #pragma unroll 4
            for (int kk = 0; kk < 32; kk += 4) {
                const int k = kx0 + kk;
                float4 x0 = ldf4(xlds + (k + 0) * BB + bq * 4);
                float4 x1 = ldf4(xlds + (k + 1) * BB + bq * 4);
                float4 x2 = ldf4(xlds + (k + 2) * BB + bq * 4);
                float4 x3 = ldf4(xlds + (k + 3) * BB + bq * 4);
                float4 wr = ldf4(wj + 0 * WP + HH + k);
                float4 wz = ldf4(wj + 1 * WP + HH + k);
                float4 wn = ldf4(wj + 2 * WP + HH + k);
                fma4(aR, wr.x, x0);  fma4(aR, wr.y, x1);  fma4(aR, wr.z, x2);  fma4(aR, wr.w, x3);
                fma4(aZ, wz.x, x0);  fma4(aZ, wz.y, x1);  fma4(aZ, wz.z, x2);  fma4(aZ, wz.w, x3);
                fma4(aIN, wn.x, x0); fma4(aIN, wn.y, x1); fma4(aIN, wn.z, x2); fma4(aIN, wn.w, x3);
            }

            part[ 0][tid] = aR.x;  part[ 4][tid] = aR.y;  part[ 8][tid] = aR.z;  part[12][tid] = aR.w;
            part[ 1][tid] = aZ.x;  part[ 5][tid] = aZ.y;  part[ 9][tid] = aZ.z;  part[13][tid] = aZ.w;
            part[ 2][tid] = aHN.x; part[ 6][tid] = aHN.y; part[10][tid] = aHN.z; part[14][tid] = aHN.w;
            part[ 3][tid] = aIN.x; part[ 7][tid] = aIN.y; part[11][tid] = aIN.z; part[15][tid] = aIN.w;
            __syncthreads();

            if (tid < 128) {
                const int j2 = tid >> 5, b = tid & 31;
                const int base = j2 * 8 + (b >> 2);
                const int i2 = b & 3;
                float sR = 0.f, sZ = 0.f, sHN = 0.f, sIN = 0.f;
                #pragma unroll
                for (int q = 0; q < 8; ++q) {
                    const int src = q * 32 + base;
                    sR  += part[i2 * 4 + 0][src];
                    sZ  += part[i2 * 4 + 1][src];
                    sHN += part[i2 * 4 + 2][src];
                    sIN += part[i2 * 4 + 3][src];
                }
                sR += blds[j2][0]; sZ += blds[j2][1];
                sIN += blds[j2][2]; sHN += blds[j2][3];
                const float r = sigmoidf_(sR);
                const float z = sigmoidf_(sZ);
                const float n = tanhf(sIN + r * sHN);
                const int jg = jc * 4 + j2;
                const float hold = hdT[(size_t)p * HH * BB + jg * BB + b];
                const float hnew = (1.0f - z) * n + z * hold;
                hdT[(size_t)(p ^ 1) * HH * BB + jg * BB + b] = hnew;
                hdrow[(size_t)b * HH + jg] = hnew;
            }
        }
        // ---- barrier A -> B ----
        __syncthreads();
        if (tid == 0)
            __hip_atomic_fetch_add(ctr, 1u, __ATOMIC_RELEASE, __HIP_MEMORY_SCOPE_AGENT);
        tgt += 256;
        if (tid == 0) {
            while (__hip_atomic_load(ctr, __ATOMIC_RELAXED, __HIP_MEMORY_SCOPE_AGENT) < tgt)
                __builtin_amdgcn_s_sleep(1);
        }
        __syncthreads();
        __builtin_amdgcn_fence(__ATOMIC_ACQUIRE, "agent");

        // ================= Phase B: logits + chunk argmax =================
        {
            const int b  = tid & 31;
            const int vg = tid >> 5;
            for (int c = bid; c < 500; c += 256) {
                const int v0 = c * 64 + vg * 8;
                float acc[8];
                #pragma unroll
                for (int i = 0; i < 8; ++i) acc[i] = 0.f;
                const float* hrow = hdrow + (size_t)b * HH;
                const float* w0   = fc_w + (size_t)v0 * HH;
                for (int k = 0; k < HH; k += 4) {
                    float4 h4 = ldf4(hrow + k);
                    #pragma unroll
                    for (int i = 0; i < 8; ++i) {
                        float4 w4 = ldf4(w0 + (size_t)i * HH + k);
                        acc[i] = fmaf(h4.x, w4.x, fmaf(h4.y, w4.y,
                                 fmaf(h4.z, w4.z, fmaf(h4.w, w4.w, acc[i]))));
                    }
                }
                #pragma unroll
                for (int i = 0; i < 8; ++i) acc[i] += fc_b[v0 + i];

                float* op = out + ((size_t)(b * TT + t)) * VV + v0;
                *reinterpret_cast<float4*>(op)     = make_float4(acc[0], acc[1], acc[2], acc[3]);
                *reinterpret_cast<float4*>(op + 4) = make_float4(acc[4], acc[5], acc[6], acc[7]);

                float best = acc[0]; int bestv = v0;
                #pragma unroll
                for (int i = 1; i < 8; ++i)
                    if (acc[i] > best) { best = acc[i]; bestv = v0 + i; }
                unsigned u = __float_as_uint(best);
                u = (u >> 31) ? ~u : (u | 0x80000000u);
                unsigned long long key =
                    ((unsigned long long)u << 32) | (0xFFFFFFFFu - (unsigned)bestv);
                lred[vg][b] = key;
                __syncthreads();
                if (tid < 32) {
                    unsigned long long km = lred[0][tid];
                    #pragma unroll
                    for (int g2 = 1; g2 < 8; ++g2) {
                        unsigned long long k2 = lred[g2][tid];
                        if (k2 > km) km = k2;
                    }
                    cand[(size_t)c * 32 + tid] = km;
                }
                __syncthreads();
            }
        }
        // ---- barrier B -> C ----
        __syncthreads();
        if (tid == 0)
            __hip_atomic_fetch_add(ctr, 1u, __ATOMIC_RELEASE, __HIP_MEMORY_SCOPE_AGENT);
        tgt += 256;
        if (tid == 0) {
            while (__hip_atomic_load(ctr, __ATOMIC_RELAXED, __HIP_MEMORY_SCOPE_AGENT) < tgt)
                __builtin_amdgcn_s_sleep(1);
        }
        __syncthreads();
        __builtin_amdgcn_fence(__ATOMIC_ACQUIRE, "agent");

        // ================= Phase C: final argmax -> tok =================
        if (bid < 32 && t < TT - 1) {
            unsigned long long km = 0ull;
            for (int c = tid; c < 500; c += 256) {
                unsigned long long k2 = cand[(size_t)c * 32 + bid];
                if (k2 > km) km = k2;
            }
            #pragma unroll
            for (int off = 32; off > 0; off >>= 1) {
                unsigned hi = (unsigned)(km >> 32), lo = (unsigned)km;
                unsigned ohi = __shfl_down(hi, off);
                unsigned olo = __shfl_down(lo, off);
                unsigned long long o = ((unsigned long long)ohi << 32) | olo;
                if (o > km) km = o;
            }
            __shared__ unsigned long long wred[4];
            if ((tid & 63) == 0) wred[tid >> 6] = km;
            __syncthreads();
            if (tid == 0) {
                km = wred[0];
                #pragma unroll
                for (int w = 1; w < 4; ++w)
                    if (wred[w] > km) km = wred[w];
                tok[bid] = (int)(0xFFFFFFFFu - (unsigned)(km & 0xFFFFFFFFull));
            }
        }
        // ---- barrier C -> next A ----
        __syncthreads();
        if (tid == 0)
            __hip_atomic_fetch_add(ctr, 1u, __ATOMIC_RELEASE, __HIP_MEMORY_SCOPE_AGENT);
        tgt += 256;
        if (tid == 0) {
            while (__hip_atomic_load(ctr, __ATOMIC_RELAXED, __HIP_MEMORY_SCOPE_AGENT) < tgt)
                __builtin_amdgcn_s_sleep(1);
        }
        __syncthreads();
        __builtin_amdgcn_fence(__ATOMIC_ACQUIRE, "agent");
    }
}

// ---------------------------------------------------------------------------
extern "C" void kernel_launch(void* const* d_in, const int* in_sizes, int n_in,
                              void* d_out, int out_size, void* d_ws, size_t ws_size,
                              hipStream_t stream) {
    (void)in_sizes; (void)n_in; (void)out_size; (void)ws_size;

    const int*   body    = (const int*)  d_in[0];
    const float* enc_emb = (const float*)d_in[2];
    const float* wih_f   = (const float*)d_in[3];
    const float* whh_f   = (const float*)d_in[4];
    const float* bih_f   = (const float*)d_in[5];
    const float* bhh_f   = (const float*)d_in[6];
    const float* wih_b   = (const float*)d_in[7];
    const float* whh_b   = (const float*)d_in[8];
    const float* bih_b   = (const float*)d_in[9];
    const float* bhh_b   = (const float*)d_in[10];
    const float* dec_emb = (const float*)d_in[11];
    const float* dwih    = (const float*)d_in[12];
    const float* dwhh    = (const float*)d_in[13];
    const float* dbih    = (const float*)d_in[14];
    const float* dbhh    = (const float*)d_in[15];
    const float* fc_w    = (const float*)d_in[16];
    const float* fc_b    = (const float*)d_in[17];
    float* out = (float*)d_out;

    char* ws = (char*)d_ws;
    float* hbufT = (float*)(ws);                    // [2][2][512][32] = 262,144 B
    float* hdT   = (float*)(ws + 262144);           // [2][512][32]    = 131,072 B
    float* hdrow = (float*)(ws + 393216);           // [32][512]       =  65,536 B
    unsigned long long* cand =
        (unsigned long long*)(ws + 458752);         // 500*32*8        = 128,000 B
    int* tok = (int*)(ws + 586752);                 // 128 B
    unsigned int* ctrE = (unsigned int*)(ws + 586880);  // 256 B (2 x 32 uints)
    unsigned int* ctrD = (unsigned int*)(ws + 587136);  // 128 B

    // re-init all cross-call state (graph-replay safe)
    hipMemsetAsync(hbufT, 0, (size_t)2 * HH * BB * sizeof(float), stream);  // parity 0
    hipMemsetAsync(ctrE, 0, 256 + 128, stream);     // ctrE + ctrD (contiguous)

    enc_persist<<<256, 256, 0, stream>>>(
        body, enc_emb, wih_f, whh_f, bih_f, bhh_f,
        wih_b, whh_b, bih_b, bhh_b, hbufT, ctrE);

    enc_fin<<<64, 256, 0, stream>>>(hbufT, hdT);

    dec_persist<<<256, 256, 0, stream>>>(
        dec_emb, dwih, dwhh, dbih, dbhh, fc_w, fc_b,
        hdT, hdrow, cand, tok, out, ctrD);
}